// Round 16
// baseline (130.784 us; speedup 1.0000x reference)
//
#include <hip/hip_runtime.h>
#include <hip/hip_bf16.h>
#include <math.h>

#define Bn 4
#define Cn 128
#define Hn 128
#define Wn 128
#define COn 128
#define HWn (Hn*Wn)        // 16384
#define NPIX (Bn*HWn)      // 65536

typedef __attribute__((ext_vector_type(8))) short bf16x8;
typedef __attribute__((ext_vector_type(4))) float f32x4;

__device__ inline unsigned short f2bf_hw(float f) {
    __hip_bfloat16 h = __float2bfloat16(f);     // HW cvt (RNE)
    return *reinterpret_cast<unsigned short*>(&h);
}
__device__ inline unsigned pack_bf2(float lo, float hi) {
    __hip_bfloat162 h2;
    h2.x = __float2bfloat16(lo);
    h2.y = __float2bfloat16(hi);                // fuses to v_cvt_pk_bf16_f32
    return *reinterpret_cast<unsigned*>(&h2);
}
__device__ inline float bflo(unsigned w) {
    union { unsigned u; float f; } cv; cv.u = w << 16; return cv.f;
}
__device__ inline float bfhi(unsigned w) {
    union { unsigned u; float f; } cv; cv.u = w & 0xffff0000u; return cv.f;
}
__device__ inline void async_copy16(const void* g, void* l) {
    __builtin_amdgcn_global_load_lds(
        (const __attribute__((address_space(1))) unsigned int*)g,
        (__attribute__((address_space(3))) unsigned int*)l, 16, 0, 0);
}

// ---------------------------------------------------------------------------
// Kernel 1: FUSED prep — transpose (blocks 0..511) + pack_w (512..583) +
// pack_ow (584..601).
// ---------------------------------------------------------------------------
__global__ __launch_bounds__(256) void k_prep(
    const float* __restrict__ x, unsigned short* __restrict__ xt,
    const float* __restrict__ dw, short* __restrict__ pw,
    const float* __restrict__ ow, short* __restrict__ pwo)
{
    __shared__ unsigned short t[Wn][Cn + 2];
    const int tid = threadIdx.x;
    const int bid = blockIdx.x;

    if (bid < 512) {
        const int bh = bid;
        const int b  = bh >> 7, h = bh & 127;
        const float* xp = x + (((size_t)b*Cn) << 14) + h*Wn;
        for (int i = tid; i < Cn*Wn; i += 256) {
            int c = i >> 7, w = i & 127;
            t[w][c] = f2bf_hw(xp[(size_t)c*HWn + w]);
        }
        __syncthreads();
        unsigned* xto = (unsigned*)(xt + ((size_t)bh << 7) * Cn);
        for (int j = tid; j < Wn*(Cn/2); j += 256) {
            int w = j >> 6, cp = j & 63;
            xto[(size_t)w*64 + cp] = *(const unsigned*)&t[w][2*cp];
        }
    } else if (bid < 584) {
        const int blk = (bid - 512)*4 + (tid >> 6);   // 0..287 (ks*8+ot)
        const int ks  = blk >> 3;
        const int ot  = blk & 7;
        const int cchunk = ks / 9;
        const int tap    = ks - cchunk*9;
        const int l   = tid & 63;
        const int oc  = ot*16 + (l & 15);
        const int kk0 = (l >> 4)*8;
        bf16x8 fr;
        #pragma unroll
        for (int j = 0; j < 8; ++j) {
            int c = cchunk*32 + kk0 + j;
            fr[j] = (short)f2bf_hw(dw[oc*1152 + c*9 + tap]);
        }
        *(bf16x8*)(pw + ((size_t)blk*64 + l)*8) = fr;
    } else {
        const int blk = (bid - 584)*4 + (tid >> 6);   // 0..71 (ks*2+ot)
        const int ks  = blk >> 1;
        const int ot  = blk & 1;
        const int cchunk = ks / 9;
        const int tap    = ks - cchunk*9;
        const int l   = tid & 63;
        const int oc  = ot*16 + (l & 15);
        const int kk0 = (l >> 4)*8;
        bf16x8 fr;
        #pragma unroll
        for (int j = 0; j < 8; ++j) {
            int c = cchunk*32 + kk0 + j;
            fr[j] = (oc < 27) ? (short)f2bf_hw(ow[oc*1152 + c*9 + tap]) : (short)0;
        }
        *(bf16x8*)(pwo + ((size_t)blk*64 + l)*8) = fr;
    }
}

// ---------------------------------------------------------------------------
// Kernel 2: FULLY FUSED deformable conv — R15 structure with both loops
// restructured as cchunk(rolled) x tap(UNROLLED): identical K-order and
// addressing, but all /9 %9 /3 %3 magic-mul sequences removed from the
// address-dependency path; tap-dependent bounds checks constant-fold in
// phase 1; lmeta reads become base+imm-offset ds_reads in phase 2.
// ---------------------------------------------------------------------------
__global__ __launch_bounds__(256) void k_deform_fused(
    const unsigned short* __restrict__ xt, const char* __restrict__ pw,
    const short* __restrict__ pwo, const float* __restrict__ ob,
    const float* __restrict__ db, float* __restrict__ out)
{
    __shared__ __align__(16) char a_lds[2][8192];
    __shared__ uint4 lmeta[64][9];                // 9216 B
    const int tid = threadIdx.x;
    const int wid = tid >> 6;
    const int l   = tid & 63;
    const int lm  = l & 15;
    const int lg  = l >> 4;
    const int bid = blockIdx.x;                   // 1024 blocks
    const int wg  = (bid & 7)*128 + (bid >> 3);   // XCD-chunked
    const int p0  = wg*64;
    const int p   = p0 + wid*16 + lm;
    const int b   = p >> 14;
    const int hw  = p & (HWn - 1);
    const int h   = hw >> 7;
    const int w   = hw & (Wn - 1);

    // ================= Phase 1: offset conv + metadata =================
    {
        f32x4 oacc[2];
        oacc[0] = (f32x4){0.f,0.f,0.f,0.f};
        oacc[1] = (f32x4){0.f,0.f,0.f,0.f};
        const int4* apg = (const int4*)pwo;

        #pragma unroll 1
        for (int cchunk = 0; cchunk < 4; ++cchunk) {
            const unsigned choff = (unsigned)(cchunk*32 + lg*8);
            const int4* apc = apg + (size_t)(cchunk*9*2)*64 + l;
            #pragma unroll
            for (int tap = 0; tap < 9; ++tap) {
                const int dyt = tap/3 - 1;          // compile-time constant
                const int dxt = tap - (tap/3)*3 - 1;
                const int y  = h + dyt;
                const int xx = w + dxt;
                const bool ok = (y >= 0) & (y < Hn) & (xx >= 0) & (xx < Wn);
                const int yc  = min(max(y, 0), Hn-1);
                const int xc  = min(max(xx, 0), Wn-1);
                int4 v = *(const int4*)(xt + (((size_t)(b*Hn + yc)*Wn + xc) << 7) + choff);
                if (!ok) v = make_int4(0,0,0,0);
                const int4* ap = apc + (size_t)(tap*2)*64;
                oacc[0] = __builtin_amdgcn_mfma_f32_16x16x32_bf16(
                    __builtin_bit_cast(bf16x8, ap[0]),  __builtin_bit_cast(bf16x8, v), oacc[0], 0, 0, 0);
                oacc[1] = __builtin_amdgcn_mfma_f32_16x16x32_bf16(
                    __builtin_bit_cast(bf16x8, ap[64]), __builtin_bit_cast(bf16x8, v), oacc[1], 0, 0, 0);
            }
        }

        // ---- dump offsets (+bias) to LDS (ol aliased into a_lds) ----
        float* ol = (float*)a_lds;                // [64 px][33] floats
        #pragma unroll
        for (int ot = 0; ot < 2; ++ot)
            #pragma unroll
            for (int r = 0; r < 4; ++r) {
                int oc = ot*16 + lg*4 + r;
                ol[(wid*16 + lm)*33 + oc] = oacc[ot][r] + ((oc < 27) ? ob[oc] : 0.0f);
            }
        // same-wave ds_write -> ds_read below; compiler inserts lgkmcnt

        // ---- metadata for this wave's 16 px x 9 taps -> LDS lmeta ----
        const int pbase = p0 + wid*16;
        for (int i = l; i < 144; i += 64) {
            const int tap = i >> 4;
            const int px  = i & 15;
            const int pp  = pbase + px;
            const int bb  = pp >> 14;
            const int hh  = (pp & (HWn-1)) >> 7;
            const int ww  = pp & 127;
            float dy = ol[(wid*16 + px)*33 + tap];
            float dx = ol[(wid*16 + px)*33 + 9 + tap];
            float mr = ol[(wid*16 + px)*33 + 18 + tap];
            float m  = 1.0f / (1.0f + __expf(-mr));
            float yf = (float)(hh + tap/3 - 1) + dy;
            float xf = (float)(ww + (tap - (tap/3)*3) - 1) + dx;
            float y0f = floorf(yf), x0f = floorf(xf);
            int   y0  = (int)y0f,  x0  = (int)x0f;
            float wy = yf - y0f, wx = xf - x0f;
            int yi0 = min(max(y0,     0), Hn-1), yi1 = min(max(y0 + 1, 0), Hn-1);
            int xi0 = min(max(x0,     0), Wn-1), xi1 = min(max(x0 + 1, 0), Wn-1);
            float vy0 = ((y0 >= 0)     & (y0 < Hn))     ? 1.0f : 0.0f;
            float vy1 = ((y0 + 1 >= 0) & (y0 + 1 < Hn)) ? 1.0f : 0.0f;
            float vx0 = ((x0 >= 0)     & (x0 < Wn))     ? 1.0f : 0.0f;
            float vx1 = ((x0 + 1 >= 0) & (x0 + 1 < Wn)) ? 1.0f : 0.0f;
            float w0_ = m * (1.0f-wy) * (1.0f-wx) * vy0 * vx0;
            float w1_ = m * (1.0f-wy) * wx        * vy0 * vx1;
            float w2_ = m * wy        * (1.0f-wx) * vy1 * vx0;
            float w3_ = m * wy        * wx        * vy1 * vx1;
            uint4 mq;
            mq.x = (unsigned)(((bb << 14) + yi0*Wn + xi0) << 8);   // byte off
            mq.y = (unsigned)((xi1 - xi0)*256) | (unsigned)((yi1 - yi0)*32768);
            mq.z = pack_bf2(w0_, w1_);
            mq.w = pack_bf2(w2_, w3_);
            lmeta[wid*16 + px][tap] = mq;
        }
    }
    __syncthreads();        // all waves done with ol region before STAGE

    // ================= Phase 2: main loop (R11 schedule, nested loops) ======
    f32x4 acc[8];
    #pragma unroll
    for (int ot = 0; ot < 8; ++ot) acc[ot] = (f32x4){0.f,0.f,0.f,0.f};

    const char* xb = (const char*)xt;
    const int   ml = wid*16 + lm;

    #define STAGE(ks_, buf_) {                                                  \
        const char* g0 = pw + (size_t)(ks_)*8192 + wid*1024 + l*16;             \
        async_copy16(g0,        (void*)&a_lds[buf_][wid*1024]);                 \
        async_copy16(g0 + 4096, (void*)&a_lds[buf_][4096 + wid*1024]);          \
    }

    STAGE(0, 0);
    int cur = 0;

    #pragma unroll 1
    for (int cchunk = 0; cchunk < 4; ++cchunk) {
        const unsigned choff = (unsigned)(cchunk*64 + lg*16);
        const int ksbase = cchunk*9;
        #pragma unroll
        for (int tap = 0; tap < 9; ++tap) {
            __syncthreads();                   // buf[cur] staged for all waves
            if (!(tap == 8 && cchunk == 3)) STAGE(ksbase + tap + 1, cur ^ 1);

            // ---- metadata from LDS: base + imm-offset ds_read_b128 ----
            const uint4 mq = lmeta[ml][tap];
            const unsigned offc = mq.x + choff;
            const unsigned dxb  = mq.y & 256u;
            const unsigned dyb  = mq.y & 32768u;

            const uint4 q0 = *(const uint4*)(xb + offc);
            const uint4 q1 = *(const uint4*)(xb + (offc + dxb));
            const uint4 q2 = *(const uint4*)(xb + (offc + dyb));
            const uint4 q3 = *(const uint4*)(xb + (offc + dyb + dxb));

            const float w0_ = bflo(mq.z), w1_ = bfhi(mq.z);
            const float w2_ = bflo(mq.w), w3_ = bfhi(mq.w);

            // ---- combine + repack to bf16 (HW cvt_pk) ----
            unsigned bw[4];
            const unsigned* u0 = (const unsigned*)&q0;
            const unsigned* u1 = (const unsigned*)&q1;
            const unsigned* u2 = (const unsigned*)&q2;
            const unsigned* u3 = (const unsigned*)&q3;
            #pragma unroll
            for (int q = 0; q < 4; ++q) {
                float lo = w0_*bflo(u0[q]) + w1_*bflo(u1[q]) + w2_*bflo(u2[q]) + w3_*bflo(u3[q]);
                float hi = w0_*bfhi(u0[q]) + w1_*bfhi(u1[q]) + w2_*bfhi(u2[q]) + w3_*bfhi(u3[q]);
                bw[q] = pack_bf2(lo, hi);
            }
            int4 bi = make_int4(bw[0], bw[1], bw[2], bw[3]);
            bf16x8 bfrag = __builtin_bit_cast(bf16x8, bi);

            // ---- 8 MFMA from LDS-staged A ----
            #pragma unroll
            for (int ot = 0; ot < 8; ++ot) {
                int4 av = *(const int4*)&a_lds[cur][(ot*64 + l)*16];
                acc[ot] = __builtin_amdgcn_mfma_f32_16x16x32_bf16(
                    __builtin_bit_cast(bf16x8, av), bfrag, acc[ot], 0, 0, 0);
            }
            cur ^= 1;
        }
    }
    #undef STAGE

    // ---- epilogue ----
    #pragma unroll
    for (int ot = 0; ot < 8; ++ot) {
        #pragma unroll
        for (int r = 0; r < 4; ++r) {
            int oc = ot*16 + lg*4 + r;
            out[((size_t)(b*COn + oc) << 14) + hw] = acc[ot][r] + db[oc];
        }
    }
}

extern "C" void kernel_launch(void* const* d_in, const int* in_sizes, int n_in,
                              void* d_out, int out_size, void* d_ws, size_t ws_size,
                              hipStream_t stream) {
    const float* x  = (const float*)d_in[0];
    const float* ow = (const float*)d_in[1];
    const float* ob = (const float*)d_in[2];
    const float* dw = (const float*)d_in[3];
    const float* db = (const float*)d_in[4];
    float* out  = (float*)d_out;

    // workspace layout (17.1 MB total)
    short*          pw  = (short*)d_ws;                             //   294,912 B
    short*          pwo = (short*)((char*)d_ws + 294912);           //    73,728 B
    unsigned short* xtp = (unsigned short*)((char*)d_ws + 368640);  // 16,777,216 B

    hipLaunchKernelGGL(k_prep, dim3(602), dim3(256), 0, stream,
                       x, xtp, dw, pw, ow, pwo);
    hipLaunchKernelGGL(k_deform_fused, dim3(NPIX/64), dim3(256), 0, stream,
                       xtp, (const char*)pw, pwo, ob, db, out);
}

// Round 17
// 112.827 us; speedup vs baseline: 1.1592x; 1.1592x over previous
//
#include <hip/hip_runtime.h>
#include <hip/hip_bf16.h>
#include <math.h>

#define Bn 4
#define Cn 128
#define Hn 128
#define Wn 128
#define COn 128
#define HWn (Hn*Wn)        // 16384
#define NPIX (Bn*HWn)      // 65536

typedef __attribute__((ext_vector_type(8))) short bf16x8;
typedef __attribute__((ext_vector_type(4))) float f32x4;

__device__ inline unsigned short f2bf_hw(float f) {
    __hip_bfloat16 h = __float2bfloat16(f);     // HW cvt (RNE)
    return *reinterpret_cast<unsigned short*>(&h);
}
__device__ inline unsigned pack_bf2(float lo, float hi) {
    __hip_bfloat162 h2;
    h2.x = __float2bfloat16(lo);
    h2.y = __float2bfloat16(hi);                // fuses to v_cvt_pk_bf16_f32
    return *reinterpret_cast<unsigned*>(&h2);
}
__device__ inline float bflo(unsigned w) {
    union { unsigned u; float f; } cv; cv.u = w << 16; return cv.f;
}
__device__ inline float bfhi(unsigned w) {
    union { unsigned u; float f; } cv; cv.u = w & 0xffff0000u; return cv.f;
}
__device__ inline void async_copy16(const void* g, void* l) {
    __builtin_amdgcn_global_load_lds(
        (const __attribute__((address_space(1))) unsigned int*)g,
        (__attribute__((address_space(3))) unsigned int*)l, 16, 0, 0);
}

// ---------------------------------------------------------------------------
// Kernel 1: FUSED prep — transpose (blocks 0..511) + pack_w (512..583) +
// pack_ow (584..601). The three jobs are independent; fusing saves 2
// launches and lets the tiny packs ride alongside the transpose.
// ---------------------------------------------------------------------------
__global__ __launch_bounds__(256) void k_prep(
    const float* __restrict__ x, unsigned short* __restrict__ xt,
    const float* __restrict__ dw, short* __restrict__ pw,
    const float* __restrict__ ow, short* __restrict__ pwo)
{
    __shared__ unsigned short t[Wn][Cn + 2];
    const int tid = threadIdx.x;
    const int bid = blockIdx.x;

    if (bid < 512) {
        // ---- NCHW f32 -> NHWC bf16 transpose; block = one (b,h) row ----
        const int bh = bid;
        const int b  = bh >> 7, h = bh & 127;
        const float* xp = x + (((size_t)b*Cn) << 14) + h*Wn;
        for (int i = tid; i < Cn*Wn; i += 256) {
            int c = i >> 7, w = i & 127;
            t[w][c] = f2bf_hw(xp[(size_t)c*HWn + w]);
        }
        __syncthreads();
        unsigned* xto = (unsigned*)(xt + ((size_t)bh << 7) * Cn);
        for (int j = tid; j < Wn*(Cn/2); j += 256) {
            int w = j >> 6, cp = j & 63;
            xto[(size_t)w*64 + cp] = *(const unsigned*)&t[w][2*cp];
        }
    } else if (bid < 584) {
        // ---- pack deform weights, K-step ks = cchunk*9 + tap ----
        const int blk = (bid - 512)*4 + (tid >> 6);   // 0..287 (ks*8+ot)
        const int ks  = blk >> 3;
        const int ot  = blk & 7;
        const int cchunk = ks / 9;
        const int tap    = ks - cchunk*9;
        const int l   = tid & 63;
        const int oc  = ot*16 + (l & 15);
        const int kk0 = (l >> 4)*8;
        bf16x8 fr;
        #pragma unroll
        for (int j = 0; j < 8; ++j) {
            int c = cchunk*32 + kk0 + j;
            fr[j] = (short)f2bf_hw(dw[oc*1152 + c*9 + tap]);
        }
        *(bf16x8*)(pw + ((size_t)blk*64 + l)*8) = fr;
    } else {
        // ---- pack offset-conv weights (27 oc padded to 32) ----
        const int blk = (bid - 584)*4 + (tid >> 6);   // 0..71 (ks*2+ot)
        const int ks  = blk >> 1;
        const int ot  = blk & 1;
        const int cchunk = ks / 9;
        const int tap    = ks - cchunk*9;
        const int l   = tid & 63;
        const int oc  = ot*16 + (l & 15);
        const int kk0 = (l >> 4)*8;
        bf16x8 fr;
        #pragma unroll
        for (int j = 0; j < 8; ++j) {
            int c = cchunk*32 + kk0 + j;
            fr[j] = (oc < 27) ? (short)f2bf_hw(ow[oc*1152 + c*9 + tap]) : (short)0;
        }
        *(bf16x8*)(pwo + ((size_t)blk*64 + l)*8) = fr;
    }
}

// ---------------------------------------------------------------------------
// Kernel 2: FULLY FUSED deformable conv (R15 — best verified variant).
// Phase 1 (prologue): offset conv via MFMA for the block's 64 px (each wave
//   its own 16 px; 36 steps x {1 bounds-checked bf16x8 load + 2 MFMA}, pwo
//   A-frags via L1 — 72KB, L2-hot). acc -> ol (aliased into a_lds) ->
//   per-(px,tap) gather metadata written DIRECTLY to LDS lmeta.
// Phase 2 (main loop): 36 K-steps (ROLLED — R5/R12/R16 all showed any
//   restructure loses to schedule), rolling 16KB A-dbuf via global_load_lds,
//   lmeta ds_read, 4 corner dwordx4, cvt_pk combine, 8 MFMA.
// LDS: a_lds 16KB (ol 8.4KB aliased inside) + lmeta 9.2KB = 25.6KB.
// ---------------------------------------------------------------------------
__global__ __launch_bounds__(256) void k_deform_fused(
    const unsigned short* __restrict__ xt, const char* __restrict__ pw,
    const short* __restrict__ pwo, const float* __restrict__ ob,
    const float* __restrict__ db, float* __restrict__ out)
{
    __shared__ __align__(16) char a_lds[2][8192];
    __shared__ uint4 lmeta[64][9];                // 9216 B
    const int tid = threadIdx.x;
    const int wid = tid >> 6;
    const int l   = tid & 63;
    const int lm  = l & 15;
    const int lg  = l >> 4;
    const int bid = blockIdx.x;                   // 1024 blocks
    const int wg  = (bid & 7)*128 + (bid >> 3);   // XCD-chunked
    const int p0  = wg*64;
    const int p   = p0 + wid*16 + lm;
    const int b   = p >> 14;
    const int hw  = p & (HWn - 1);
    const int h   = hw >> 7;
    const int w   = hw & (Wn - 1);

    // ================= Phase 1: offset conv + metadata =================
    {
        f32x4 oacc[2];
        oacc[0] = (f32x4){0.f,0.f,0.f,0.f};
        oacc[1] = (f32x4){0.f,0.f,0.f,0.f};
        const int4* apg = (const int4*)pwo;

        #pragma unroll 1
        for (int ks = 0; ks < 36; ++ks) {
            const int cchunk = ks / 9;
            const int tap    = ks - cchunk*9;
            const int y  = h + tap/3 - 1;
            const int xx = w + (tap - (tap/3)*3) - 1;
            const bool ok = (y >= 0) & (y < Hn) & (xx >= 0) & (xx < Wn);
            const int yc  = min(max(y, 0), Hn-1);
            const int xc  = min(max(xx, 0), Wn-1);
            int4 v = *(const int4*)(xt + (((size_t)(b*Hn + yc)*Wn + xc) << 7)
                                       + cchunk*32 + lg*8);
            if (!ok) v = make_int4(0,0,0,0);
            const int4* ap = apg + (size_t)(ks*2)*64 + l;
            oacc[0] = __builtin_amdgcn_mfma_f32_16x16x32_bf16(
                __builtin_bit_cast(bf16x8, ap[0]),  __builtin_bit_cast(bf16x8, v), oacc[0], 0, 0, 0);
            oacc[1] = __builtin_amdgcn_mfma_f32_16x16x32_bf16(
                __builtin_bit_cast(bf16x8, ap[64]), __builtin_bit_cast(bf16x8, v), oacc[1], 0, 0, 0);
        }

        // ---- dump offsets (+bias) to LDS (ol aliased into a_lds) ----
        float* ol = (float*)a_lds;                // [64 px][33] floats
        #pragma unroll
        for (int ot = 0; ot < 2; ++ot)
            #pragma unroll
            for (int r = 0; r < 4; ++r) {
                int oc = ot*16 + lg*4 + r;
                ol[(wid*16 + lm)*33 + oc] = oacc[ot][r] + ((oc < 27) ? ob[oc] : 0.0f);
            }
        // same-wave ds_write -> ds_read below; compiler inserts lgkmcnt

        // ---- metadata for this wave's 16 px x 9 taps -> LDS lmeta ----
        const int pbase = p0 + wid*16;
        for (int i = l; i < 144; i += 64) {
            const int tap = i >> 4;
            const int px  = i & 15;
            const int pp  = pbase + px;
            const int bb  = pp >> 14;
            const int hh  = (pp & (HWn-1)) >> 7;
            const int ww  = pp & 127;
            float dy = ol[(wid*16 + px)*33 + tap];
            float dx = ol[(wid*16 + px)*33 + 9 + tap];
            float mr = ol[(wid*16 + px)*33 + 18 + tap];
            float m  = 1.0f / (1.0f + __expf(-mr));
            float yf = (float)(hh + tap/3 - 1) + dy;
            float xf = (float)(ww + (tap - (tap/3)*3) - 1) + dx;
            float y0f = floorf(yf), x0f = floorf(xf);
            int   y0  = (int)y0f,  x0  = (int)x0f;
            float wy = yf - y0f, wx = xf - x0f;
            int yi0 = min(max(y0,     0), Hn-1), yi1 = min(max(y0 + 1, 0), Hn-1);
            int xi0 = min(max(x0,     0), Wn-1), xi1 = min(max(x0 + 1, 0), Wn-1);
            float vy0 = ((y0 >= 0)     & (y0 < Hn))     ? 1.0f : 0.0f;
            float vy1 = ((y0 + 1 >= 0) & (y0 + 1 < Hn)) ? 1.0f : 0.0f;
            float vx0 = ((x0 >= 0)     & (x0 < Wn))     ? 1.0f : 0.0f;
            float vx1 = ((x0 + 1 >= 0) & (x0 + 1 < Wn)) ? 1.0f : 0.0f;
            float w0_ = m * (1.0f-wy) * (1.0f-wx) * vy0 * vx0;
            float w1_ = m * (1.0f-wy) * wx        * vy0 * vx1;
            float w2_ = m * wy        * (1.0f-wx) * vy1 * vx0;
            float w3_ = m * wy        * wx        * vy1 * vx1;
            uint4 mq;
            mq.x = (unsigned)(((bb << 14) + yi0*Wn + xi0) << 8);   // byte off
            mq.y = (unsigned)((xi1 - xi0)*256) | (unsigned)((yi1 - yi0)*32768);
            mq.z = pack_bf2(w0_, w1_);
            mq.w = pack_bf2(w2_, w3_);
            lmeta[wid*16 + px][tap] = mq;
        }
    }
    __syncthreads();        // all waves done with ol region before STAGE

    // ================= Phase 2: main loop (R11 schedule, rolled) ==========
    f32x4 acc[8];
    #pragma unroll
    for (int ot = 0; ot < 8; ++ot) acc[ot] = (f32x4){0.f,0.f,0.f,0.f};

    const char* xb = (const char*)xt;
    const int   ml = wid*16 + lm;

    #define STAGE(ks_, buf_) {                                                  \
        const char* g0 = pw + (size_t)(ks_)*8192 + wid*1024 + l*16;             \
        async_copy16(g0,        (void*)&a_lds[buf_][wid*1024]);                 \
        async_copy16(g0 + 4096, (void*)&a_lds[buf_][4096 + wid*1024]);          \
    }

    STAGE(0, 0);
    int cur = 0;

    #pragma unroll 1
    for (int ks = 0; ks < 36; ++ks) {
        const int cchunk = ks / 9;
        const int tap    = ks - cchunk*9;
        __syncthreads();                       // buf[cur] staged for all waves
        if (ks + 1 < 36) STAGE(ks + 1, cur ^ 1);

        // ---- metadata from LDS: broadcast ds_read_b128, no VMEM dep ----
        const uint4 mq = lmeta[ml][tap];
        const unsigned offc = mq.x + (unsigned)(cchunk*64 + lg*16);
        const unsigned dxb  = mq.y & 256u;
        const unsigned dyb  = mq.y & 32768u;

        const uint4 q0 = *(const uint4*)(xb + offc);
        const uint4 q1 = *(const uint4*)(xb + (offc + dxb));
        const uint4 q2 = *(const uint4*)(xb + (offc + dyb));
        const uint4 q3 = *(const uint4*)(xb + (offc + dyb + dxb));

        const float w0_ = bflo(mq.z), w1_ = bfhi(mq.z);
        const float w2_ = bflo(mq.w), w3_ = bfhi(mq.w);

        // ---- combine + repack to bf16 (HW cvt_pk) ----
        unsigned bw[4];
        const unsigned* u0 = (const unsigned*)&q0;
        const unsigned* u1 = (const unsigned*)&q1;
        const unsigned* u2 = (const unsigned*)&q2;
        const unsigned* u3 = (const unsigned*)&q3;
        #pragma unroll
        for (int q = 0; q < 4; ++q) {
            float lo = w0_*bflo(u0[q]) + w1_*bflo(u1[q]) + w2_*bflo(u2[q]) + w3_*bflo(u3[q]);
            float hi = w0_*bfhi(u0[q]) + w1_*bfhi(u1[q]) + w2_*bfhi(u2[q]) + w3_*bfhi(u3[q]);
            bw[q] = pack_bf2(lo, hi);
        }
        int4 bi = make_int4(bw[0], bw[1], bw[2], bw[3]);
        bf16x8 bfrag = __builtin_bit_cast(bf16x8, bi);

        // ---- 8 MFMA from LDS-staged A ----
        #pragma unroll
        for (int ot = 0; ot < 8; ++ot) {
            int4 av = *(const int4*)&a_lds[cur][(ot*64 + l)*16];
            acc[ot] = __builtin_amdgcn_mfma_f32_16x16x32_bf16(
                __builtin_bit_cast(bf16x8, av), bfrag, acc[ot], 0, 0, 0);
        }
        cur ^= 1;
    }
    #undef STAGE

    // ---- epilogue ----
    #pragma unroll
    for (int ot = 0; ot < 8; ++ot) {
        #pragma unroll
        for (int r = 0; r < 4; ++r) {
            int oc = ot*16 + lg*4 + r;
            out[((size_t)(b*COn + oc) << 14) + hw] = acc[ot][r] + db[oc];
        }
    }
}

extern "C" void kernel_launch(void* const* d_in, const int* in_sizes, int n_in,
                              void* d_out, int out_size, void* d_ws, size_t ws_size,
                              hipStream_t stream) {
    const float* x  = (const float*)d_in[0];
    const float* ow = (const float*)d_in[1];
    const float* ob = (const float*)d_in[2];
    const float* dw = (const float*)d_in[3];
    const float* db = (const float*)d_in[4];
    float* out  = (float*)d_out;

    // workspace layout (17.1 MB total; meta buffer eliminated)
    short*          pw  = (short*)d_ws;                             //   294,912 B
    short*          pwo = (short*)((char*)d_ws + 294912);           //    73,728 B
    unsigned short* xtp = (unsigned short*)((char*)d_ws + 368640);  // 16,777,216 B

    hipLaunchKernelGGL(k_prep, dim3(602), dim3(256), 0, stream,
                       x, xtp, dw, pw, ow, pwo);
    hipLaunchKernelGGL(k_deform_fused, dim3(NPIX/64), dim3(256), 0, stream,
                       xtp, (const char*)pw, pwo, ob, db, out);
}